// Round 1
// baseline (1633.027 us; speedup 1.0000x reference)
//
#include <hip/hip_runtime.h>

#define VQSIZE 2048
#define DIM 64
#define BATCH 32
#define FEAT 4096
#define NROWS (BATCH*FEAT)        // 131072
#define DECAYF 0.99f
#define ONEMD 0.01f
#define EPSF 1e-5f

// ---- workspace layout (float offsets) ----
#define WS_CS     0                       // [2048] cs_batch
#define WS_EMBSUM 2048                    // [2048*64] emb_sum
#define WS_LOSS   (2048 + VQSIZE*DIM)     // [1] loss accumulator
#define WS_SMOOTH (WS_LOSS + 1)           // [2048] smoothed denom
#define WS_ENORM  (WS_SMOOTH + VQSIZE)    // [2048] ||e||^2
#define WS_ZERO_FLOATS (WS_LOSS + 1)      // region that must start at 0

// ---- output layout (float offsets, concatenated in return order) ----
#define OUT_QUANT 0                         // [32*64*4096]
#define OUT_IDX   (BATCH*DIM*FEAT)          // [131072] (written as float)
#define OUT_LOSS  (OUT_IDX + NROWS)         // [1]
#define OUT_NEMB  (OUT_LOSS + 1)            // [2048*64]
#define OUT_NCS   (OUT_NEMB + VQSIZE*DIM)   // [2048]
#define OUT_NEA   (OUT_NCS + VQSIZE)        // [2048*64]

__global__ void enorm_kernel(const float* __restrict__ emb, float* __restrict__ ws) {
    int e = blockIdx.x * blockDim.x + threadIdx.x;   // 0..2047
    const float4* p = (const float4*)(emb + (size_t)e * DIM);
    float s = 0.f;
#pragma unroll
    for (int i = 0; i < 16; ++i) {
        float4 v = p[i];
        s += v.x*v.x + v.y*v.y + v.z*v.z + v.w*v.w;
    }
    ws[WS_ENORM + e] = s;
}

#define ETILE 128

__launch_bounds__(256)
__global__ void assign_kernel(const float* __restrict__ in,
                              const float* __restrict__ emb,
                              float* __restrict__ out,
                              float* __restrict__ ws) {
    __shared__ float se[ETILE * DIM];
    __shared__ float sn[ETILE];
    __shared__ float lred[4];

    const int r = blockIdx.x * 256 + threadIdx.x;    // row id 0..131071
    const int b = r >> 12;                           // / FEAT
    const int f = r & (FEAT - 1);
    const float* xin = in + (size_t)b * DIM * FEAT + f;

    // load row into registers (coalesced across lanes per channel)
    float x[DIM];
#pragma unroll
    for (int c = 0; c < DIM; ++c) x[c] = xin[(size_t)c * FEAT];

    float best = 3.4e38f;
    int bidx = 0;

    for (int t = 0; t < VQSIZE; t += ETILE) {
        __syncthreads();
        // stage codebook tile (contiguous chunk) into LDS
        const float4* src = (const float4*)(emb + (size_t)t * DIM);
        float4* dst = (float4*)se;
        for (int i = threadIdx.x; i < ETILE * DIM / 4; i += 256) dst[i] = src[i];
        if (threadIdx.x < ETILE) sn[threadIdx.x] = ws[WS_ENORM + t + threadIdx.x];
        __syncthreads();

        for (int e = 0; e < ETILE; ++e) {
            const float4* ep = (const float4*)(se + e * DIM);
            float a0 = 0.f, a1 = 0.f, a2 = 0.f, a3 = 0.f;
#pragma unroll
            for (int c4 = 0; c4 < 16; ++c4) {
                float4 v = ep[c4];                    // LDS broadcast read
                a0 += x[c4*4 + 0] * v.x;
                a1 += x[c4*4 + 1] * v.y;
                a2 += x[c4*4 + 2] * v.z;
                a3 += x[c4*4 + 3] * v.w;
            }
            float score = sn[e] - 2.f * ((a0 + a1) + (a2 + a3));
            if (score < best) { best = score; bidx = t + e; }   // strict <: first-index tie-break
        }
    }

    // ---- fused epilogue ----
    out[OUT_IDX + r] = (float)bidx;

    const float4* eq = (const float4*)(emb + (size_t)bidx * DIM);
    float* qout = out + (size_t)b * DIM * FEAT + f;
    float* embsum = ws + WS_EMBSUM + (size_t)bidx * DIM;
    float lsum = 0.f;
#pragma unroll
    for (int c4 = 0; c4 < 16; ++c4) {
        float4 q = eq[c4];                            // L2-resident gather
        const float qv[4] = {q.x, q.y, q.z, q.w};
#pragma unroll
        for (int k = 0; k < 4; ++k) {
            int c = c4*4 + k;
            qout[(size_t)c * FEAT] = qv[k];           // coalesced per channel
            float d = x[c] - qv[k];
            lsum += d * d;
            atomicAdd(&embsum[c], x[c]);
        }
    }
    atomicAdd(&ws[WS_CS + bidx], 1.0f);

    // block-reduce commitment loss, one atomic per block
#pragma unroll
    for (int off = 32; off; off >>= 1) lsum += __shfl_down(lsum, off, 64);
    int wid = threadIdx.x >> 6, lane = threadIdx.x & 63;
    if (lane == 0) lred[wid] = lsum;
    __syncthreads();
    if (threadIdx.x == 0)
        atomicAdd(&ws[WS_LOSS], lred[0] + lred[1] + lred[2] + lred[3]);
}

__launch_bounds__(1024)
__global__ void finalize_cs(const float* __restrict__ cs,
                            float* __restrict__ out,
                            float* __restrict__ ws) {
    __shared__ float red[16];
    const int t = threadIdx.x;                       // 0..1023, 2 entries each
    float ncs0 = DECAYF * cs[t]        + ONEMD * ws[WS_CS + t];
    float ncs1 = DECAYF * cs[t + 1024] + ONEMD * ws[WS_CS + t + 1024];
    out[OUT_NCS + t]        = ncs0;
    out[OUT_NCS + t + 1024] = ncs1;

    float s = ncs0 + ncs1;
#pragma unroll
    for (int off = 32; off; off >>= 1) s += __shfl_down(s, off, 64);
    int wid = t >> 6, lane = t & 63;
    if (lane == 0) red[wid] = s;
    __syncthreads();
    if (t < 64) {
        float v = (t < 16) ? red[t] : 0.f;
#pragma unroll
        for (int off = 8; off; off >>= 1) v += __shfl_down(v, off, 64);
        if (t == 0) red[0] = v;
    }
    __syncthreads();
    const float n = red[0];
    const float nmax = fmaxf(n, 1.0f);
    const float inv_denom = 1.0f / (n + (float)VQSIZE * EPSF);
    ws[WS_SMOOTH + t]        = (ncs0 + EPSF) * inv_denom * nmax;
    ws[WS_SMOOTH + t + 1024] = (ncs1 + EPSF) * inv_denom * nmax;
    if (t == 0) out[OUT_LOSS] = ws[WS_LOSS] * (1.0f / ((float)NROWS * (float)DIM));
}

__global__ void finalize_emb(const float* __restrict__ ea,
                             float* __restrict__ out,
                             const float* __restrict__ ws) {
    int i = blockIdx.x * 256 + threadIdx.x;          // 0..131071
    int e = i >> 6;
    float nea = DECAYF * ea[i] + ONEMD * ws[WS_EMBSUM + i];
    out[OUT_NEA + i] = nea;
    out[OUT_NEMB + i] = nea / ws[WS_SMOOTH + e];
}

extern "C" void kernel_launch(void* const* d_in, const int* in_sizes, int n_in,
                              void* d_out, int out_size, void* d_ws, size_t ws_size,
                              hipStream_t stream) {
    const float* inputs    = (const float*)d_in[0];
    const float* embedding = (const float*)d_in[1];
    const float* emb_avg   = (const float*)d_in[2];
    const float* cluster   = (const float*)d_in[3];
    float* out = (float*)d_out;
    float* ws  = (float*)d_ws;

    // zero the accumulator region (ws is poisoned 0xAA before every launch)
    hipMemsetAsync(ws, 0, (size_t)WS_ZERO_FLOATS * sizeof(float), stream);

    enorm_kernel<<<VQSIZE / 256, 256, 0, stream>>>(embedding, ws);
    assign_kernel<<<NROWS / 256, 256, 0, stream>>>(inputs, embedding, out, ws);
    finalize_cs<<<1, 1024, 0, stream>>>(cluster, out, ws);
    finalize_emb<<<VQSIZE * DIM / 256, 256, 0, stream>>>(emb_avg, out, ws);
}

// Round 2
// 1055.751 us; speedup vs baseline: 1.5468x; 1.5468x over previous
//
#include <hip/hip_runtime.h>

#define VQSIZE 2048
#define DIM 64
#define BATCH 32
#define FEAT 4096
#define NROWS (BATCH*FEAT)        // 131072
#define DECAYF 0.99f
#define ONEMD 0.01f
#define EPSF 1e-5f

// ---- workspace layout (float offsets) ----
#define WS_CS     0                       // [2048] cs_batch
#define WS_EMBSUM 2048                    // [2048*64] emb_sum
#define WS_LOSS   (2048 + VQSIZE*DIM)     // [1] loss accumulator
#define WS_SMOOTH (WS_LOSS + 1)           // [2048] smoothed denom
#define WS_ENORM  (WS_SMOOTH + VQSIZE)    // [2048] ||e||^2
#define WS_ZERO_FLOATS (WS_LOSS + 1)      // [0, WS_LOSS] must start at 0

// ---- output layout (float offsets, concatenated in return order) ----
#define OUT_QUANT 0                         // [32*64*4096]
#define OUT_IDX   (BATCH*DIM*FEAT)          // [131072] (written as float)
#define OUT_LOSS  (OUT_IDX + NROWS)         // [1]
#define OUT_NEMB  (OUT_LOSS + 1)            // [2048*64]
#define OUT_NCS   (OUT_NEMB + VQSIZE*DIM)   // [2048]
#define OUT_NEA   (OUT_NCS + VQSIZE)        // [2048*64]

__global__ void enorm_kernel(const float* __restrict__ emb, float* __restrict__ ws) {
    int e = blockIdx.x * blockDim.x + threadIdx.x;   // 0..2047
    const float4* p = (const float4*)(emb + (size_t)e * DIM);
    float s = 0.f;
#pragma unroll
    for (int i = 0; i < 16; ++i) {
        float4 v = p[i];
        s += v.x*v.x + v.y*v.y + v.z*v.z + v.w*v.w;
    }
    ws[WS_ENORM + e] = s;
}

// ---------------------------------------------------------------------------
// assign2d: block tile 128 rows x 128 entries, thread tile 8x8 outer product.
// LDS: sa[64][132] (x^T tile), sb[64][132] (emb^T chunk), snb[128] (||e||^2).
// Stride 132 floats: b128 reads land on 8 banks 2-way (free per m136).
// ---------------------------------------------------------------------------
#define APAD 132
#define SA_FLOATS (64*APAD)
#define SB_FLOATS (64*APAD)

__launch_bounds__(256, 2)
__global__ void assign2d_kernel(const float* __restrict__ in,
                                const float* __restrict__ emb,
                                float* __restrict__ out,
                                const float* __restrict__ ws) {
    __shared__ float smem[SA_FLOATS + SB_FLOATS + 128];
    float* sa  = smem;                    // [64][APAD] : sa[c][r]
    float* sb  = smem + SA_FLOATS;        // [64][APAD] : sb[c][e]
    float* snb = smem + SA_FLOATS + SB_FLOATS;

    const int t  = threadIdx.x;
    const int tx = t & 15;                // row group
    const int ty = t >> 4;                // entry group
    const int rbase = blockIdx.x * 128;   // 128 consecutive rows, same b
    const int b = rbase >> 12;
    const int f0 = rbase & (FEAT - 1);

    // ---- stage A tile: sa[c][r] = in[b][c][f0+r], coalesced float4 reads ----
    {
        const int c = t >> 2;
        const int r0 = (t & 3) * 32;
        const float* src = in + (size_t)b * DIM * FEAT + (size_t)c * FEAT + f0 + r0;
        float* dst = sa + c * APAD + r0;
#pragma unroll
        for (int j = 0; j < 8; ++j) {
            float4 v = *(const float4*)(src + j * 4);
            *(float4*)(dst + j * 4) = v;
        }
    }

    float acc[8][8];
#pragma unroll
    for (int j = 0; j < 8; ++j)
#pragma unroll
        for (int i = 0; i < 8; ++i) acc[j][i] = 0.f;

    float best[8];
    int   bidx[8];
#pragma unroll
    for (int j = 0; j < 8; ++j) { best[j] = 3.4e38f; bidx[j] = 0; }

    for (int ec = 0; ec < VQSIZE / 128; ++ec) {
        __syncthreads();
        // ---- stage B chunk transposed: sb[c][e] = emb[ec*128+e][c] ----
        {
            const float* src = emb + (size_t)ec * 128 * DIM;
#pragma unroll
            for (int j = 0; j < 8; ++j) {
                int q = j * 256 + t;              // float4 index, coalesced
                float4 v = *(const float4*)(src + q * 4);
                int e = q >> 4;
                int c = (q & 15) * 4;
                sb[(c + 0) * APAD + e] = v.x;
                sb[(c + 1) * APAD + e] = v.y;
                sb[(c + 2) * APAD + e] = v.z;
                sb[(c + 3) * APAD + e] = v.w;
            }
            if (t < 128) snb[t] = ws[WS_ENORM + ec * 128 + t];
        }
        __syncthreads();

        // ---- 8x8 outer-product accumulation over k=0..63 ----
#pragma unroll 2
        for (int k = 0; k < DIM; ++k) {
            float4 a0 = *(const float4*)(sa + k * APAD + tx * 4);
            float4 a1 = *(const float4*)(sa + k * APAD + 64 + tx * 4);
            float4 b0 = *(const float4*)(sb + k * APAD + ty * 4);
            float4 b1 = *(const float4*)(sb + k * APAD + 64 + ty * 4);
            const float av[8] = {a0.x,a0.y,a0.z,a0.w,a1.x,a1.y,a1.z,a1.w};
            const float bv[8] = {b0.x,b0.y,b0.z,b0.w,b1.x,b1.y,b1.z,b1.w};
#pragma unroll
            for (int j = 0; j < 8; ++j)
#pragma unroll
                for (int i = 0; i < 8; ++i)
                    acc[j][i] += av[j] * bv[i];
        }

        // ---- fold into running argmin (strict lexicographic (score, idx)) ----
#pragma unroll
        for (int j = 0; j < 8; ++j) {
#pragma unroll
            for (int i = 0; i < 8; ++i) {
                int e_loc = (i < 4) ? (ty * 4 + i) : (64 + ty * 4 + (i - 4));
                float s = snb[e_loc] - 2.f * acc[j][i];
                int eg = ec * 128 + e_loc;
                if (s < best[j] || (s == best[j] && eg < bidx[j])) {
                    best[j] = s; bidx[j] = eg;
                }
                acc[j][i] = 0.f;
            }
        }
    }

    // ---- cross-thread reduce over the 16 entry groups ----
    __syncthreads();                       // sa region now dead; reuse it
    float* rs = smem;                      // [128][17]
    int*   ri = (int*)(smem + 128 * 17);   // [128][17]
#pragma unroll
    for (int j = 0; j < 8; ++j) {
        int row = (j < 4) ? (tx * 4 + j) : (64 + tx * 4 + (j - 4));
        rs[row * 17 + ty] = best[j];
        ri[row * 17 + ty] = bidx[j];
    }
    __syncthreads();
    if (t < 128) {
        float bs = rs[t * 17];
        int   bi = ri[t * 17];
#pragma unroll
        for (int q = 1; q < 16; ++q) {
            float s = rs[t * 17 + q];
            int   i = ri[t * 17 + q];
            if (s < bs || (s == bs && i < bi)) { bs = s; bi = i; }
        }
        out[OUT_IDX + rbase + t] = (float)bi;
    }
}

// ---------------------------------------------------------------------------
// epilogue: quantized write + commitment loss + EMA scatter accumulators
// ---------------------------------------------------------------------------
__launch_bounds__(256)
__global__ void epilogue_kernel(const float* __restrict__ in,
                                const float* __restrict__ emb,
                                float* __restrict__ out,
                                float* __restrict__ ws) {
    __shared__ float lred[4];
    const int r = blockIdx.x * 256 + threadIdx.x;
    const int b = r >> 12;
    const int f = r & (FEAT - 1);

    const int idx = (int)out[OUT_IDX + r];
    const float4* eq = (const float4*)(emb + (size_t)idx * DIM);
    const float* xin = in + (size_t)b * DIM * FEAT + f;
    float* qout = out + (size_t)b * DIM * FEAT + f;
    float* es = ws + WS_EMBSUM + (size_t)idx * DIM;

    float lsum = 0.f;
#pragma unroll
    for (int c4 = 0; c4 < 16; ++c4) {
        float4 e4 = eq[c4];
        const float ev[4] = {e4.x, e4.y, e4.z, e4.w};
#pragma unroll
        for (int m = 0; m < 4; ++m) {
            int c = c4 * 4 + m;
            float xv = xin[(size_t)c * FEAT];
            qout[(size_t)c * FEAT] = ev[m];
            float d = xv - ev[m];
            lsum += d * d;
            atomicAdd(&es[c], xv);
        }
    }
    atomicAdd(&ws[WS_CS + idx], 1.0f);

#pragma unroll
    for (int off = 32; off; off >>= 1) lsum += __shfl_down(lsum, off, 64);
    int wid = threadIdx.x >> 6, lane = threadIdx.x & 63;
    if (lane == 0) lred[wid] = lsum;
    __syncthreads();
    if (threadIdx.x == 0)
        atomicAdd(&ws[WS_LOSS], lred[0] + lred[1] + lred[2] + lred[3]);
}

__launch_bounds__(1024)
__global__ void finalize_cs(const float* __restrict__ cs,
                            float* __restrict__ out,
                            float* __restrict__ ws) {
    __shared__ float red[16];
    const int t = threadIdx.x;                       // 0..1023, 2 entries each
    float ncs0 = DECAYF * cs[t]        + ONEMD * ws[WS_CS + t];
    float ncs1 = DECAYF * cs[t + 1024] + ONEMD * ws[WS_CS + t + 1024];
    out[OUT_NCS + t]        = ncs0;
    out[OUT_NCS + t + 1024] = ncs1;

    float s = ncs0 + ncs1;
#pragma unroll
    for (int off = 32; off; off >>= 1) s += __shfl_down(s, off, 64);
    int wid = t >> 6, lane = t & 63;
    if (lane == 0) red[wid] = s;
    __syncthreads();
    if (t < 64) {
        float v = (t < 16) ? red[t] : 0.f;
#pragma unroll
        for (int off = 8; off; off >>= 1) v += __shfl_down(v, off, 64);
        if (t == 0) red[0] = v;
    }
    __syncthreads();
    const float n = red[0];
    const float nmax = fmaxf(n, 1.0f);
    const float inv_denom = 1.0f / (n + (float)VQSIZE * EPSF);
    ws[WS_SMOOTH + t]        = (ncs0 + EPSF) * inv_denom * nmax;
    ws[WS_SMOOTH + t + 1024] = (ncs1 + EPSF) * inv_denom * nmax;
    if (t == 0) out[OUT_LOSS] = ws[WS_LOSS] * (1.0f / ((float)NROWS * (float)DIM));
}

__global__ void finalize_emb(const float* __restrict__ ea,
                             float* __restrict__ out,
                             const float* __restrict__ ws) {
    int i = blockIdx.x * 256 + threadIdx.x;          // 0..131071
    int e = i >> 6;
    float nea = DECAYF * ea[i] + ONEMD * ws[WS_EMBSUM + i];
    out[OUT_NEA + i] = nea;
    out[OUT_NEMB + i] = nea / ws[WS_SMOOTH + e];
}

extern "C" void kernel_launch(void* const* d_in, const int* in_sizes, int n_in,
                              void* d_out, int out_size, void* d_ws, size_t ws_size,
                              hipStream_t stream) {
    const float* inputs    = (const float*)d_in[0];
    const float* embedding = (const float*)d_in[1];
    const float* emb_avg   = (const float*)d_in[2];
    const float* cluster   = (const float*)d_in[3];
    float* out = (float*)d_out;
    float* ws  = (float*)d_ws;

    // zero the accumulator region (ws is poisoned 0xAA before every launch)
    hipMemsetAsync(ws, 0, (size_t)WS_ZERO_FLOATS * sizeof(float), stream);

    enorm_kernel<<<VQSIZE / 256, 256, 0, stream>>>(embedding, ws);
    assign2d_kernel<<<NROWS / 128, 256, 0, stream>>>(inputs, embedding, out, ws);
    epilogue_kernel<<<NROWS / 256, 256, 0, stream>>>(inputs, embedding, out, ws);
    finalize_cs<<<1, 1024, 0, stream>>>(cluster, out, ws);
    finalize_emb<<<VQSIZE * DIM / 256, 256, 0, stream>>>(emb_avg, out, ws);
}

// Round 7
// 390.230 us; speedup vs baseline: 4.1848x; 2.7055x over previous
//
#include <hip/hip_runtime.h>
#include <stdint.h>

#define VQSIZE 2048
#define DIM 64
#define BATCH 32
#define FEAT 4096
#define NROWS (BATCH*FEAT)        // 131072
#define DECAYF 0.99f
#define ONEMD 0.01f
#define EPSF 1e-5f
#define MARGIN 2e-3f              // > 2*eps_max of split-bf16 score error
#define RCAP 8192

typedef __attribute__((ext_vector_type(8))) short bf16x8;   // 8 bf16 bit patterns (4 VGPR)
typedef __attribute__((ext_vector_type(4))) float f32x4;

// ---- workspace layout (float offsets) ----
#define WS_CS     0                         // [2048]
#define WS_EMBSUM 2048                      // [2048*64]
#define WS_LOSS   (WS_EMBSUM + VQSIZE*DIM)  // 133120
#define WS_RC_I   (WS_LOSS + 1)             // [1] int rescue count (zeroed)
#define WS_SMOOTH (WS_LOSS + 2)             // [2048] -> ends 135170
#define WS_ENORM  135172                    // [2048] fp32, 16B aligned -> ends 137220
#define WS_EHI_F  137220                    // 2048*64 bf16 = 262144 B = 65536 floats
#define WS_ELO_F  (WS_EHI_F + 65536)        // 202756, same size
#define WS_RLIST  (WS_ELO_F + 65536)        // 268292 [RCAP ints]  (was ALIASED to ELO -> r6 bug)
#define WS_ZERO_FLOATS (WS_LOSS + 2)        // [0, WS_RC_I] must start at 0

// ---- output layout (float offsets) ----
#define OUT_QUANT 0
#define OUT_IDX   (BATCH*DIM*FEAT)
#define OUT_LOSS  (OUT_IDX + NROWS)
#define OUT_NEMB  (OUT_LOSS + 1)
#define OUT_NCS   (OUT_NEMB + VQSIZE*DIM)
#define OUT_NEA   (OUT_NCS + VQSIZE)

// byte offset of element (row, k) inside a [T][64]bf16 tile, XOR-swizzled so
// ds_read_b128 of a 16-row column slice is bank-conflict-free (T2 / G4).
__device__ __forceinline__ int swz(int row, int k) {
    return row * 128 + ((((k >> 3) ^ (row & 7))) << 4) + ((k & 7) << 1);
}

__device__ __forceinline__ uint16_t f2bf(float x) {          // RNE bf16 bits
    uint32_t u = __builtin_bit_cast(uint32_t, x);
    u += 0x7fff + ((u >> 16) & 1);
    return (uint16_t)(u >> 16);
}
__device__ __forceinline__ float bf2f(uint16_t b) {
    return __builtin_bit_cast(float, (uint32_t)b << 16);
}

__device__ __forceinline__ void gload16(const void* g, void* l) {
    __builtin_amdgcn_global_load_lds(
        (const __attribute__((address_space(1))) uint32_t*)g,
        (__attribute__((address_space(3))) uint32_t*)l, 16, 0, 0);
}

// ---------------------------------------------------------------------------
// prep: ||e||^2 (fp32) + codebook split into pre-swizzled bf16 hi/lo arrays
// ---------------------------------------------------------------------------
__global__ void prep_kernel(const float* __restrict__ emb, float* __restrict__ ws) {
    const int e = blockIdx.x * 256 + threadIdx.x;            // 0..2047
    const float* er = emb + (size_t)e * DIM;
    char* ehi = (char*)(ws + WS_EHI_F) + (e >> 7) * 16384;
    char* elo = (char*)(ws + WS_ELO_F) + (e >> 7) * 16384;
    const int erow = e & 127;
    float s = 0.f;
#pragma unroll
    for (int k = 0; k < DIM; k += 2) {
        float x0 = er[k], x1 = er[k + 1];
        s += x0 * x0 + x1 * x1;
        uint16_t h0 = f2bf(x0), h1 = f2bf(x1);
        uint16_t l0 = f2bf(x0 - bf2f(h0)), l1 = f2bf(x1 - bf2f(h1));
        int off = swz(erow, k);
        *(uint32_t*)(ehi + off) = (uint32_t)h0 | ((uint32_t)h1 << 16);
        *(uint32_t*)(elo + off) = (uint32_t)l0 | ((uint32_t)l1 << 16);
    }
    ws[WS_ENORM + e] = s;
}

// ---------------------------------------------------------------------------
// assign: block = 4 waves x 32 rows = 128 rows, all 2048 entries via MFMA.
// Tracks best + second-best; near-margin rows go to the rescue worklist.
// ---------------------------------------------------------------------------
#define NCHUNK (VQSIZE/128)
#define MFMA(a, b, c) __builtin_amdgcn_mfma_f32_16x16x32_bf16(a, b, c, 0, 0, 0)

__launch_bounds__(256, 2)
__global__ void assign_mfma_kernel(const float* __restrict__ in,
                                   float* __restrict__ ws,
                                   float* __restrict__ out) {
    __shared__ __align__(16) char sXhi[16384];   // [128 rows][64 k] bf16, swizzled
    __shared__ __align__(16) char sXlo[16384];
    __shared__ __align__(16) char sEhi[16384];   // [128 entries][64 k] bf16, swizzled
    __shared__ __align__(16) char sElo[16384];
    __shared__ __align__(16) float sNorm[VQSIZE];

    const int t = threadIdx.x;
    const int lane = t & 63;
    const int w = t >> 6;
    const int rbase = blockIdx.x * 128;
    const int b = rbase >> 12;
    const int f0 = rbase & (FEAT - 1);

    // ---- stage X tile: read fp32 coalesced, split hi/lo, swizzled LDS write ----
    {
        const float* base = in + (size_t)b * DIM * FEAT + f0;
#pragma unroll
        for (int i = 0; i < 4; ++i) {
            const int c0 = ((t >> 5) & 7) * 2 + i * 16;      // even channel pair
#pragma unroll
            for (int m = 0; m < 4; ++m) {
                const int r = (t & 31) + m * 32;
                float x0 = base[(size_t)c0 * FEAT + r];
                float x1 = base[(size_t)(c0 + 1) * FEAT + r];
                uint16_t h0 = f2bf(x0), h1 = f2bf(x1);
                uint16_t l0 = f2bf(x0 - bf2f(h0)), l1 = f2bf(x1 - bf2f(h1));
                int off = swz(r, c0);
                *(uint32_t*)(sXhi + off) = (uint32_t)h0 | ((uint32_t)h1 << 16);
                *(uint32_t*)(sXlo + off) = (uint32_t)l0 | ((uint32_t)l1 << 16);
            }
        }
    }
    // ---- stage all 2048 ||e||^2 (8KB) ----
    {
        const char* gsrc = (const char*)(ws + WS_ENORM);
#pragma unroll
        for (int q = 0; q < 2; ++q) {
            int off = (w * 2 + q) * 1024;
            gload16(gsrc + off + lane * 16, (char*)sNorm + off);
        }
    }
    __syncthreads();

    // ---- X fragments -> registers (reused across all 2048 entries) ----
    bf16x8 xh[2][2], xl[2][2];
    {
        const int rl = w * 32 + (lane & 15);
        const int kb0 = (lane >> 4) * 8;
#pragma unroll
        for (int rt = 0; rt < 2; ++rt)
#pragma unroll
            for (int s = 0; s < 2; ++s) {
                int off = swz(rl + rt * 16, s * 32 + kb0);
                xh[rt][s] = *(const bf16x8*)(sXhi + off);
                xl[rt][s] = *(const bf16x8*)(sXlo + off);
            }
    }

    float best0 = 3.4e38f, best1 = 3.4e38f;
    float sec0  = 3.4e38f, sec1  = 3.4e38f;
    int bidx0 = 0, bidx1 = 0;
    const char* gEhi = (const char*)(ws + WS_EHI_F);
    const char* gElo = (const char*)(ws + WS_ELO_F);
    const int kb = (lane >> 4) * 8;
    const int jbase = (lane >> 4) * 4;

    for (int chunk = 0; chunk < NCHUNK; ++chunk) {
        __syncthreads();                          // previous chunk compute done
        {   // stage E chunk (32KB) via async global->LDS, pre-swizzled source
            const char* gh = gEhi + chunk * 16384 + w * 4096 + lane * 16;
            const char* gl = gElo + chunk * 16384 + w * 4096 + lane * 16;
            char* lh = sEhi + w * 4096;
            char* ll = sElo + w * 4096;
#pragma unroll
            for (int q = 0; q < 4; ++q) {
                gload16(gh + q * 1024, lh + q * 1024);
                gload16(gl + q * 1024, ll + q * 1024);
            }
        }
        __syncthreads();                          // barrier drains vmcnt

#pragma unroll 2
        for (int et = 0; et < 8; ++et) {
            const int er = et * 16 + (lane & 15);
            bf16x8 eh0 = *(const bf16x8*)(sEhi + swz(er, kb));
            bf16x8 eh1 = *(const bf16x8*)(sEhi + swz(er, 32 + kb));
            bf16x8 el0 = *(const bf16x8*)(sElo + swz(er, kb));
            bf16x8 el1 = *(const bf16x8*)(sElo + swz(er, 32 + kb));
            f32x4 en = *(const f32x4*)(sNorm + chunk * 128 + et * 16 + jbase);

            f32x4 acc0 = {0.f, 0.f, 0.f, 0.f};
            f32x4 acc1 = {0.f, 0.f, 0.f, 0.f};
            acc0 = MFMA(eh0, xh[0][0], acc0);     // hi . hi
            acc1 = MFMA(eh0, xh[1][0], acc1);
            acc0 = MFMA(eh1, xh[0][1], acc0);
            acc1 = MFMA(eh1, xh[1][1], acc1);
            acc0 = MFMA(el0, xh[0][0], acc0);     // lo(E) . hi(X)
            acc1 = MFMA(el0, xh[1][0], acc1);
            acc0 = MFMA(el1, xh[0][1], acc0);
            acc1 = MFMA(el1, xh[1][1], acc1);
            acc0 = MFMA(eh0, xl[0][0], acc0);     // hi(E) . lo(X)
            acc1 = MFMA(eh0, xl[1][0], acc1);
            acc0 = MFMA(eh1, xl[0][1], acc0);
            acc1 = MFMA(eh1, xl[1][1], acc1);

            const int eib = chunk * 128 + et * 16 + jbase;
#pragma unroll
            for (int j = 0; j < 4; ++j) {         // indices ascend within lane
                float s0 = fmaf(acc0[j], -2.f, en[j]);
                if (s0 < best0) { sec0 = best0; best0 = s0; bidx0 = eib + j; }
                else            sec0 = fminf(sec0, s0);
                float s1 = fmaf(acc1[j], -2.f, en[j]);
                if (s1 < best1) { sec1 = best1; best1 = s1; bidx1 = eib + j; }
                else            sec1 = fminf(sec1, s1);
            }
        }
    }

    // ---- cross-lane (best, idx, sec) merge over the 4 entry groups ----
#pragma unroll
    for (int off = 16; off <= 32; off <<= 1) {
        float ob = __shfl_xor(best0, off); int oi = __shfl_xor(bidx0, off);
        float os = __shfl_xor(sec0, off);
        bool take = (ob < best0) || (ob == best0 && oi < bidx0);
        sec0 = take ? fminf(best0, os) : fminf(ob, sec0);
        if (take) { best0 = ob; bidx0 = oi; }

        ob = __shfl_xor(best1, off); oi = __shfl_xor(bidx1, off);
        os = __shfl_xor(sec1, off);
        take = (ob < best1) || (ob == best1 && oi < bidx1);
        sec1 = take ? fminf(best1, os) : fminf(ob, sec1);
        if (take) { best1 = ob; bidx1 = oi; }
    }
    if (lane < 16) {
        int* wsi = (int*)ws;
        int row0 = rbase + w * 32 + lane;
        int row1 = row0 + 16;
        out[OUT_IDX + row0] = (float)bidx0;
        out[OUT_IDX + row1] = (float)bidx1;
        if (sec0 - best0 < MARGIN) {              // near-tie: exact fp32 rescue
            int slot = atomicAdd(&wsi[WS_RC_I], 1);
            if (slot < RCAP) wsi[WS_RLIST + slot] = row0;
        }
        if (sec1 - best1 < MARGIN) {
            int slot = atomicAdd(&wsi[WS_RC_I], 1);
            if (slot < RCAP) wsi[WS_RLIST + slot] = row1;
        }
    }
}

// ---------------------------------------------------------------------------
// rescue: exact fp32 argmin for flagged rows (same formula as round-2 pass)
// ---------------------------------------------------------------------------
__launch_bounds__(256)
__global__ void rescue_kernel(const float* __restrict__ in,
                              const float* __restrict__ emb,
                              const float* __restrict__ ws,
                              float* __restrict__ out) {
    __shared__ float sx[8][64];
    __shared__ int   srow[8];
    __shared__ float rs[256];
    __shared__ int   ri[256];
    const int t = threadIdx.x;
    const int* wsi = (const int*)ws;
    int cnt = wsi[WS_RC_I];
    if (cnt > RCAP) cnt = RCAP;

    for (int base = blockIdx.x * 8; base < cnt; base += gridDim.x * 8) {
        int nr = cnt - base; if (nr > 8) nr = 8;
        if (t < 8) srow[t] = (t < nr) ? wsi[WS_RLIST + base + t] : 0;
        __syncthreads();
        {
            int rr = t >> 5;                     // 8 rows x 32 threads
            int k = (t & 31) * 2;
            if (rr < nr) {
                int row = srow[rr];
                int b = row >> 12, f = row & (FEAT - 1);
                const float* xin = in + (size_t)b * DIM * FEAT + f;
                sx[rr][k]     = xin[(size_t)k * FEAT];
                sx[rr][k + 1] = xin[(size_t)(k + 1) * FEAT];
            }
        }
        __syncthreads();
        for (int rr = 0; rr < nr; ++rr) {
            float bs = 3.4e38f; int bi = 0;
            for (int q = 0; q < 8; ++q) {
                int e = t * 8 + q;               // ascending within thread
                const float4* ep = (const float4*)(emb + (size_t)e * DIM);
                float acc = 0.f;
#pragma unroll
                for (int k4 = 0; k4 < 16; ++k4) {
                    float4 v = ep[k4];
                    acc += sx[rr][k4*4]*v.x + sx[rr][k4*4+1]*v.y
                         + sx[rr][k4*4+2]*v.z + sx[rr][k4*4+3]*v.w;
                }
                float s = ws[WS_ENORM + e] - 2.f * acc;
                if (s < bs) { bs = s; bi = e; }  // strict <: first index wins
            }
            rs[t] = bs; ri[t] = bi;
            __syncthreads();
            for (int off2 = 128; off2; off2 >>= 1) {
                if (t < off2) {
                    float o = rs[t + off2]; int oi2 = ri[t + off2];
                    if (o < rs[t] || (o == rs[t] && oi2 < ri[t])) { rs[t] = o; ri[t] = oi2; }
                }
                __syncthreads();
            }
            if (t == 0) out[OUT_IDX + srow[rr]] = (float)ri[0];
            __syncthreads();
        }
        __syncthreads();
    }
}

// ---------------------------------------------------------------------------
// epilogue: quant write + loss (coalesced), then wave-per-row coalesced
// 256B atomic bursts for emb_sum via LDS transpose.
// ---------------------------------------------------------------------------
__launch_bounds__(256, 2)
__global__ void epilogue_kernel(const float* __restrict__ in,
                                const float* __restrict__ emb,
                                float* __restrict__ out,
                                float* __restrict__ ws) {
    __shared__ float sx[64 * 265];               // [c][r], stride 265 (odd -> 2-way)
    __shared__ int   sidx[256];
    __shared__ float lred[4];

    const int t = threadIdx.x;
    const int r = blockIdx.x * 256 + t;
    const int b = r >> 12;
    const int f = r & (FEAT - 1);

    const int idx = (int)out[OUT_IDX + r];
    sidx[t] = idx;
    atomicAdd(&ws[WS_CS + idx], 1.0f);

    const float4* eq = (const float4*)(emb + (size_t)idx * DIM);
    const float* xin = in + (size_t)b * DIM * FEAT + f;
    float* qout = out + (size_t)b * DIM * FEAT + f;
    float lsum = 0.f;
#pragma unroll
    for (int c4 = 0; c4 < 16; ++c4) {
        float4 e4 = eq[c4];
        const float ev[4] = {e4.x, e4.y, e4.z, e4.w};
#pragma unroll
        for (int m = 0; m < 4; ++m) {
            int c = c4 * 4 + m;
            float xv = xin[(size_t)c * FEAT];
            qout[(size_t)c * FEAT] = ev[m];
            float d = xv - ev[m];
            lsum += d * d;
            sx[c * 265 + t] = xv;
        }
    }
#pragma unroll
    for (int off = 32; off; off >>= 1) lsum += __shfl_down(lsum, off, 64);
    if ((t & 63) == 0) lred[t >> 6] = lsum;
    __syncthreads();
    if (t == 0) atomicAdd(&ws[WS_LOSS], lred[0] + lred[1] + lred[2] + lred[3]);

    // phase B: lane = channel, one coalesced 64-lane atomic burst per row
    const int w = t >> 6, lane = t & 63;
    float* es = ws + WS_EMBSUM;
    for (int q = 0; q < 64; ++q) {
        int rr = w * 64 + q;
        atomicAdd(es + (size_t)sidx[rr] * 64 + lane, sx[lane * 265 + rr]);
    }
}

__launch_bounds__(1024)
__global__ void finalize_cs(const float* __restrict__ cs,
                            float* __restrict__ out,
                            float* __restrict__ ws) {
    __shared__ float red[16];
    const int t = threadIdx.x;
    float ncs0 = DECAYF * cs[t]        + ONEMD * ws[WS_CS + t];
    float ncs1 = DECAYF * cs[t + 1024] + ONEMD * ws[WS_CS + t + 1024];
    out[OUT_NCS + t]        = ncs0;
    out[OUT_NCS + t + 1024] = ncs1;

    float s = ncs0 + ncs1;
#pragma unroll
    for (int off = 32; off; off >>= 1) s += __shfl_down(s, off, 64);
    int wid = t >> 6, lane = t & 63;
    if (lane == 0) red[wid] = s;
    __syncthreads();
    if (t < 64) {
        float v = (t < 16) ? red[t] : 0.f;
#pragma unroll
        for (int off = 8; off; off >>= 1) v += __shfl_down(v, off, 64);
        if (t == 0) red[0] = v;
    }
    __syncthreads();
    const float n = red[0];
    const float nmax = fmaxf(n, 1.0f);
    const float inv_denom = 1.0f / (n + (float)VQSIZE * EPSF);
    ws[WS_SMOOTH + t]        = (ncs0 + EPSF) * inv_denom * nmax;
    ws[WS_SMOOTH + t + 1024] = (ncs1 + EPSF) * inv_denom * nmax;
    if (t == 0) out[OUT_LOSS] = ws[WS_LOSS] * (1.0f / ((float)NROWS * (float)DIM));
}

__global__ void finalize_emb(const float* __restrict__ ea,
                             float* __restrict__ out,
                             const float* __restrict__ ws) {
    int i = blockIdx.x * 256 + threadIdx.x;
    int e = i >> 6;
    float nea = DECAYF * ea[i] + ONEMD * ws[WS_EMBSUM + i];
    out[OUT_NEA + i] = nea;
    out[OUT_NEMB + i] = nea / ws[WS_SMOOTH + e];
}

extern "C" void kernel_launch(void* const* d_in, const int* in_sizes, int n_in,
                              void* d_out, int out_size, void* d_ws, size_t ws_size,
                              hipStream_t stream) {
    const float* inputs    = (const float*)d_in[0];
    const float* embedding = (const float*)d_in[1];
    const float* emb_avg   = (const float*)d_in[2];
    const float* cluster   = (const float*)d_in[3];
    float* out = (float*)d_out;
    float* ws  = (float*)d_ws;

    hipMemsetAsync(ws, 0, (size_t)WS_ZERO_FLOATS * sizeof(float), stream);

    prep_kernel<<<VQSIZE / 256, 256, 0, stream>>>(embedding, ws);
    assign_mfma_kernel<<<NROWS / 128, 256, 0, stream>>>(inputs, ws, out);
    rescue_kernel<<<256, 256, 0, stream>>>(inputs, embedding, ws, out);
    epilogue_kernel<<<NROWS / 256, 256, 0, stream>>>(inputs, embedding, out, ws);
    finalize_cs<<<1, 1024, 0, stream>>>(cluster, out, ws);
    finalize_emb<<<VQSIZE * DIM / 256, 256, 0, stream>>>(emb_avg, out, ws);
}

// Round 8
// 338.451 us; speedup vs baseline: 4.8250x; 1.1530x over previous
//
#include <hip/hip_runtime.h>
#include <stdint.h>

#define VQSIZE 2048
#define DIM 64
#define BATCH 32
#define FEAT 4096
#define NROWS (BATCH*FEAT)        // 131072
#define DECAYF 0.99f
#define ONEMD 0.01f
#define EPSF 1e-5f
#define MARGIN 5e-4f              // > conservative worst-case split-bf16 err 4.2e-4
#define RCAP 8192
#define RGRID 256                 // rescue grid (blocks)

typedef __attribute__((ext_vector_type(8))) short bf16x8;   // 8 bf16 bit patterns (4 VGPR)
typedef __attribute__((ext_vector_type(4))) float f32x4;

// ---- workspace layout (float offsets) ----
#define WS_CS     0                         // [2048]
#define WS_EMBSUM 2048                      // [2048*64]
#define WS_LOSS   (WS_EMBSUM + VQSIZE*DIM)  // 133120
#define WS_RC_I   (WS_LOSS + 1)             // [1] int rescue count (zeroed)
#define WS_SMOOTH (WS_LOSS + 2)             // [2048] -> ends 135170
#define WS_ENORM  135172                    // [2048] fp32, 16B aligned -> ends 137220
#define WS_EHI_F  137220                    // 2048*64 bf16 = 262144 B = 65536 floats
#define WS_ELO_F  (WS_EHI_F + 65536)        // 202756, same size
#define WS_RLIST  (WS_ELO_F + 65536)        // 268292 [RCAP ints]
#define WS_ZERO_FLOATS (WS_LOSS + 2)        // [0, WS_RC_I] must start at 0

// ---- output layout (float offsets) ----
#define OUT_QUANT 0
#define OUT_IDX   (BATCH*DIM*FEAT)
#define OUT_LOSS  (OUT_IDX + NROWS)
#define OUT_NEMB  (OUT_LOSS + 1)
#define OUT_NCS   (OUT_NEMB + VQSIZE*DIM)
#define OUT_NEA   (OUT_NCS + VQSIZE)

// byte offset of element (row, k) inside a [T][64]bf16 tile, XOR-swizzled so
// ds_read_b128 of a 16-row column slice is bank-conflict-free (T2 / G4).
__device__ __forceinline__ int swz(int row, int k) {
    return row * 128 + ((((k >> 3) ^ (row & 7))) << 4) + ((k & 7) << 1);
}

__device__ __forceinline__ uint16_t f2bf(float x) {          // RNE bf16 bits
    uint32_t u = __builtin_bit_cast(uint32_t, x);
    u += 0x7fff + ((u >> 16) & 1);
    return (uint16_t)(u >> 16);
}
__device__ __forceinline__ float bf2f(uint16_t b) {
    return __builtin_bit_cast(float, (uint32_t)b << 16);
}

__device__ __forceinline__ void gload16(const void* g, void* l) {
    __builtin_amdgcn_global_load_lds(
        (const __attribute__((address_space(1))) uint32_t*)g,
        (__attribute__((address_space(3))) uint32_t*)l, 16, 0, 0);
}

// ---------------------------------------------------------------------------
// prep: ||e||^2 (fp32) + codebook split into pre-swizzled bf16 hi/lo arrays
// ---------------------------------------------------------------------------
__global__ void prep_kernel(const float* __restrict__ emb, float* __restrict__ ws) {
    const int e = blockIdx.x * 256 + threadIdx.x;            // 0..2047
    const float* er = emb + (size_t)e * DIM;
    char* ehi = (char*)(ws + WS_EHI_F) + (e >> 7) * 16384;
    char* elo = (char*)(ws + WS_ELO_F) + (e >> 7) * 16384;
    const int erow = e & 127;
    float s = 0.f;
#pragma unroll
    for (int k = 0; k < DIM; k += 2) {
        float x0 = er[k], x1 = er[k + 1];
        s += x0 * x0 + x1 * x1;
        uint16_t h0 = f2bf(x0), h1 = f2bf(x1);
        uint16_t l0 = f2bf(x0 - bf2f(h0)), l1 = f2bf(x1 - bf2f(h1));
        int off = swz(erow, k);
        *(uint32_t*)(ehi + off) = (uint32_t)h0 | ((uint32_t)h1 << 16);
        *(uint32_t*)(elo + off) = (uint32_t)l0 | ((uint32_t)l1 << 16);
    }
    ws[WS_ENORM + e] = s;
}

// ---------------------------------------------------------------------------
// assign: block = 4 waves x 32 rows = 128 rows, all 2048 entries via MFMA.
// Tracks best + second-best; near-margin rows go to the rescue worklist.
// ---------------------------------------------------------------------------
#define NCHUNK (VQSIZE/128)
#define MFMA(a, b, c) __builtin_amdgcn_mfma_f32_16x16x32_bf16(a, b, c, 0, 0, 0)

__launch_bounds__(256, 2)
__global__ void assign_mfma_kernel(const float* __restrict__ in,
                                   float* __restrict__ ws,
                                   float* __restrict__ out) {
    __shared__ __align__(16) char sXhi[16384];   // [128 rows][64 k] bf16, swizzled
    __shared__ __align__(16) char sXlo[16384];
    __shared__ __align__(16) char sEhi[16384];   // [128 entries][64 k] bf16, swizzled
    __shared__ __align__(16) char sElo[16384];
    __shared__ __align__(16) float sNorm[VQSIZE];

    const int t = threadIdx.x;
    const int lane = t & 63;
    const int w = t >> 6;
    const int rbase = blockIdx.x * 128;
    const int b = rbase >> 12;
    const int f0 = rbase & (FEAT - 1);

    // ---- stage X tile: read fp32 coalesced, split hi/lo, swizzled LDS write ----
    {
        const float* base = in + (size_t)b * DIM * FEAT + f0;
#pragma unroll
        for (int i = 0; i < 4; ++i) {
            const int c0 = ((t >> 5) & 7) * 2 + i * 16;      // even channel pair
#pragma unroll
            for (int m = 0; m < 4; ++m) {
                const int r = (t & 31) + m * 32;
                float x0 = base[(size_t)c0 * FEAT + r];
                float x1 = base[(size_t)(c0 + 1) * FEAT + r];
                uint16_t h0 = f2bf(x0), h1 = f2bf(x1);
                uint16_t l0 = f2bf(x0 - bf2f(h0)), l1 = f2bf(x1 - bf2f(h1));
                int off = swz(r, c0);
                *(uint32_t*)(sXhi + off) = (uint32_t)h0 | ((uint32_t)h1 << 16);
                *(uint32_t*)(sXlo + off) = (uint32_t)l0 | ((uint32_t)l1 << 16);
            }
        }
    }
    // ---- stage all 2048 ||e||^2 (8KB) ----
    {
        const char* gsrc = (const char*)(ws + WS_ENORM);
#pragma unroll
        for (int q = 0; q < 2; ++q) {
            int off = (w * 2 + q) * 1024;
            gload16(gsrc + off + lane * 16, (char*)sNorm + off);
        }
    }
    __syncthreads();

    // ---- X fragments -> registers (reused across all 2048 entries) ----
    bf16x8 xh[2][2], xl[2][2];
    {
        const int rl = w * 32 + (lane & 15);
        const int kb0 = (lane >> 4) * 8;
#pragma unroll
        for (int rt = 0; rt < 2; ++rt)
#pragma unroll
            for (int s = 0; s < 2; ++s) {
                int off = swz(rl + rt * 16, s * 32 + kb0);
                xh[rt][s] = *(const bf16x8*)(sXhi + off);
                xl[rt][s] = *(const bf16x8*)(sXlo + off);
            }
    }

    float best0 = 3.4e38f, best1 = 3.4e38f;
    float sec0  = 3.4e38f, sec1  = 3.4e38f;
    int bidx0 = 0, bidx1 = 0;
    const char* gEhi = (const char*)(ws + WS_EHI_F);
    const char* gElo = (const char*)(ws + WS_ELO_F);
    const int kb = (lane >> 4) * 8;
    const int jbase = (lane >> 4) * 4;

    for (int chunk = 0; chunk < NCHUNK; ++chunk) {
        __syncthreads();                          // previous chunk compute done
        {   // stage E chunk (32KB) via async global->LDS, pre-swizzled source
            const char* gh = gEhi + chunk * 16384 + w * 4096 + lane * 16;
            const char* gl = gElo + chunk * 16384 + w * 4096 + lane * 16;
            char* lh = sEhi + w * 4096;
            char* ll = sElo + w * 4096;
#pragma unroll
            for (int q = 0; q < 4; ++q) {
                gload16(gh + q * 1024, lh + q * 1024);
                gload16(gl + q * 1024, ll + q * 1024);
            }
        }
        __syncthreads();                          // barrier drains vmcnt

#pragma unroll 2
        for (int et = 0; et < 8; ++et) {
            const int er = et * 16 + (lane & 15);
            bf16x8 eh0 = *(const bf16x8*)(sEhi + swz(er, kb));
            bf16x8 eh1 = *(const bf16x8*)(sEhi + swz(er, 32 + kb));
            bf16x8 el0 = *(const bf16x8*)(sElo + swz(er, kb));
            bf16x8 el1 = *(const bf16x8*)(sElo + swz(er, 32 + kb));
            f32x4 en = *(const f32x4*)(sNorm + chunk * 128 + et * 16 + jbase);

            f32x4 acc0 = {0.f, 0.f, 0.f, 0.f};
            f32x4 acc1 = {0.f, 0.f, 0.f, 0.f};
            acc0 = MFMA(eh0, xh[0][0], acc0);     // hi . hi
            acc1 = MFMA(eh0, xh[1][0], acc1);
            acc0 = MFMA(eh1, xh[0][1], acc0);
            acc1 = MFMA(eh1, xh[1][1], acc1);
            acc0 = MFMA(el0, xh[0][0], acc0);     // lo(E) . hi(X)
            acc1 = MFMA(el0, xh[1][0], acc1);
            acc0 = MFMA(el1, xh[0][1], acc0);
            acc1 = MFMA(el1, xh[1][1], acc1);
            acc0 = MFMA(eh0, xl[0][0], acc0);     // hi(E) . lo(X)
            acc1 = MFMA(eh0, xl[1][0], acc1);
            acc0 = MFMA(eh1, xl[0][1], acc0);
            acc1 = MFMA(eh1, xl[1][1], acc1);

            const int eib = chunk * 128 + et * 16 + jbase;
#pragma unroll
            for (int j = 0; j < 4; ++j) {         // indices ascend within lane
                float s0 = fmaf(acc0[j], -2.f, en[j]);
                if (s0 < best0) { sec0 = best0; best0 = s0; bidx0 = eib + j; }
                else            sec0 = fminf(sec0, s0);
                float s1 = fmaf(acc1[j], -2.f, en[j]);
                if (s1 < best1) { sec1 = best1; best1 = s1; bidx1 = eib + j; }
                else            sec1 = fminf(sec1, s1);
            }
        }
    }

    // ---- cross-lane (best, idx, sec) merge over the 4 entry groups ----
#pragma unroll
    for (int off = 16; off <= 32; off <<= 1) {
        float ob = __shfl_xor(best0, off); int oi = __shfl_xor(bidx0, off);
        float os = __shfl_xor(sec0, off);
        bool take = (ob < best0) || (ob == best0 && oi < bidx0);
        sec0 = take ? fminf(best0, os) : fminf(ob, sec0);
        if (take) { best0 = ob; bidx0 = oi; }

        ob = __shfl_xor(best1, off); oi = __shfl_xor(bidx1, off);
        os = __shfl_xor(sec1, off);
        take = (ob < best1) || (ob == best1 && oi < bidx1);
        sec1 = take ? fminf(best1, os) : fminf(ob, sec1);
        if (take) { best1 = ob; bidx1 = oi; }
    }
    if (lane < 16) {
        int* wsi = (int*)ws;
        int row0 = rbase + w * 32 + lane;
        int row1 = row0 + 16;
        out[OUT_IDX + row0] = (float)bidx0;
        out[OUT_IDX + row1] = (float)bidx1;
        if (sec0 - best0 < MARGIN) {              // near-tie: exact fp32 rescue
            int slot = atomicAdd(&wsi[WS_RC_I], 1);
            if (slot < RCAP) wsi[WS_RLIST + slot] = row0;
        }
        if (sec1 - best1 < MARGIN) {
            int slot = atomicAdd(&wsi[WS_RC_I], 1);
            if (slot < RCAP) wsi[WS_RLIST + slot] = row1;
        }
    }
}

// ---------------------------------------------------------------------------
// rescue v2: one wave per flagged row. x broadcast via per-wave LDS buffer;
// lane l scans entries [32l, 32l+32) ascending; lex shfl_xor argmin merge.
// ---------------------------------------------------------------------------
__launch_bounds__(256)
__global__ void rescue_kernel(const float* __restrict__ in,
                              const float* __restrict__ emb,
                              const float* __restrict__ ws,
                              float* __restrict__ out) {
    __shared__ float xbuf[4][64];
    const int t = threadIdx.x;
    const int w = t >> 6, lane = t & 63;
    const int* wsi = (const int*)ws;
    int cnt = wsi[WS_RC_I];
    if (cnt > RCAP) cnt = RCAP;
    const int nbat = (cnt + 4 * RGRID - 1) / (4 * RGRID);    // uniform trip count

    for (int it = 0; it < nbat; ++it) {
        const int i = (it * RGRID + blockIdx.x) * 4 + w;
        const bool active = i < cnt;
        const int row = active ? wsi[WS_RLIST + i] : 0;
        const int b = row >> 12, f = row & (FEAT - 1);
        xbuf[w][lane] = in[(size_t)b * DIM * FEAT + (size_t)lane * FEAT + f];
        __syncthreads();                          // uniform; xbuf ready

        float bs = 3.4e38f; int bi = 0;
        const int e0 = lane * 32;
        for (int q = 0; q < 32; ++q) {
            const int e = e0 + q;                 // ascending within lane
            const float4* ep = (const float4*)(emb + (size_t)e * DIM);
            float a0 = 0.f, a1 = 0.f, a2 = 0.f, a3 = 0.f;
#pragma unroll
            for (int k4 = 0; k4 < 16; ++k4) {
                float4 v = ep[k4];                // contiguous 256B per lane (L2)
                a0 += xbuf[w][k4*4 + 0] * v.x;    // LDS broadcast reads (free)
                a1 += xbuf[w][k4*4 + 1] * v.y;
                a2 += xbuf[w][k4*4 + 2] * v.z;
                a3 += xbuf[w][k4*4 + 3] * v.w;
            }
            float s = ws[WS_ENORM + e] - 2.f * ((a0 + a1) + (a2 + a3));
            if (s < bs) { bs = s; bi = e; }       // strict <: first index wins
        }
#pragma unroll
        for (int off = 1; off <= 32; off <<= 1) { // lex merge across 64 lanes
            float ob = __shfl_xor(bs, off); int oi = __shfl_xor(bi, off);
            if (ob < bs || (ob == bs && oi < bi)) { bs = ob; bi = oi; }
        }
        if (active && lane == 0) out[OUT_IDX + row] = (float)bi;
        __syncthreads();                          // uniform; before xbuf overwrite
    }
}

// ---------------------------------------------------------------------------
// epilogue: quant write + loss (coalesced), then wave-per-row coalesced
// 256B atomic bursts for emb_sum via LDS transpose.
// ---------------------------------------------------------------------------
__launch_bounds__(256, 2)
__global__ void epilogue_kernel(const float* __restrict__ in,
                                const float* __restrict__ emb,
                                float* __restrict__ out,
                                float* __restrict__ ws) {
    __shared__ float sx[64 * 265];               // [c][r], stride 265 (odd -> 2-way)
    __shared__ int   sidx[256];
    __shared__ float lred[4];

    const int t = threadIdx.x;
    const int r = blockIdx.x * 256 + t;
    const int b = r >> 12;
    const int f = r & (FEAT - 1);

    const int idx = (int)out[OUT_IDX + r];
    sidx[t] = idx;
    atomicAdd(&ws[WS_CS + idx], 1.0f);

    const float4* eq = (const float4*)(emb + (size_t)idx * DIM);
    const float* xin = in + (size_t)b * DIM * FEAT + f;
    float* qout = out + (size_t)b * DIM * FEAT + f;
    float lsum = 0.f;
#pragma unroll
    for (int c4 = 0; c4 < 16; ++c4) {
        float4 e4 = eq[c4];
        const float ev[4] = {e4.x, e4.y, e4.z, e4.w};
#pragma unroll
        for (int m = 0; m < 4; ++m) {
            int c = c4 * 4 + m;
            float xv = xin[(size_t)c * FEAT];
            qout[(size_t)c * FEAT] = ev[m];
            float d = xv - ev[m];
            lsum += d * d;
            sx[c * 265 + t] = xv;
        }
    }
#pragma unroll
    for (int off = 32; off; off >>= 1) lsum += __shfl_down(lsum, off, 64);
    if ((t & 63) == 0) lred[t >> 6] = lsum;
    __syncthreads();
    if (t == 0) atomicAdd(&ws[WS_LOSS], lred[0] + lred[1] + lred[2] + lred[3]);

    // phase B: lane = channel, one coalesced 64-lane atomic burst per row
    const int w = t >> 6, lane = t & 63;
    float* es = ws + WS_EMBSUM;
    for (int q = 0; q < 64; ++q) {
        int rr = w * 64 + q;
        atomicAdd(es + (size_t)sidx[rr] * 64 + lane, sx[lane * 265 + rr]);
    }
}

__launch_bounds__(1024)
__global__ void finalize_cs(const float* __restrict__ cs,
                            float* __restrict__ out,
                            float* __restrict__ ws) {
    __shared__ float red[16];
    const int t = threadIdx.x;
    float ncs0 = DECAYF * cs[t]        + ONEMD * ws[WS_CS + t];
    float ncs1 = DECAYF * cs[t + 1024] + ONEMD * ws[WS_CS + t + 1024];
    out[OUT_NCS + t]        = ncs0;
    out[OUT_NCS + t + 1024] = ncs1;

    float s = ncs0 + ncs1;
#pragma unroll
    for (int off = 32; off; off >>= 1) s += __shfl_down(s, off, 64);
    int wid = t >> 6, lane = t & 63;
    if (lane == 0) red[wid] = s;
    __syncthreads();
    if (t < 64) {
        float v = (t < 16) ? red[t] : 0.f;
#pragma unroll
        for (int off = 8; off; off >>= 1) v += __shfl_down(v, off, 64);
        if (t == 0) red[0] = v;
    }
    __syncthreads();
    const float n = red[0];
    const float nmax = fmaxf(n, 1.0f);
    const float inv_denom = 1.0f / (n + (float)VQSIZE * EPSF);
    ws[WS_SMOOTH + t]        = (ncs0 + EPSF) * inv_denom * nmax;
    ws[WS_SMOOTH + t + 1024] = (ncs1 + EPSF) * inv_denom * nmax;
    if (t == 0) out[OUT_LOSS] = ws[WS_LOSS] * (1.0f / ((float)NROWS * (float)DIM));
}

__global__ void finalize_emb(const float* __restrict__ ea,
                             float* __restrict__ out,
                             const float* __restrict__ ws) {
    int i = blockIdx.x * 256 + threadIdx.x;
    int e = i >> 6;
    float nea = DECAYF * ea[i] + ONEMD * ws[WS_EMBSUM + i];
    out[OUT_NEA + i] = nea;
    out[OUT_NEMB + i] = nea / ws[WS_SMOOTH + e];
}

extern "C" void kernel_launch(void* const* d_in, const int* in_sizes, int n_in,
                              void* d_out, int out_size, void* d_ws, size_t ws_size,
                              hipStream_t stream) {
    const float* inputs    = (const float*)d_in[0];
    const float* embedding = (const float*)d_in[1];
    const float* emb_avg   = (const float*)d_in[2];
    const float* cluster   = (const float*)d_in[3];
    float* out = (float*)d_out;
    float* ws  = (float*)d_ws;

    hipMemsetAsync(ws, 0, (size_t)WS_ZERO_FLOATS * sizeof(float), stream);

    prep_kernel<<<VQSIZE / 256, 256, 0, stream>>>(embedding, ws);
    assign_mfma_kernel<<<NROWS / 128, 256, 0, stream>>>(inputs, ws, out);
    rescue_kernel<<<RGRID, 256, 0, stream>>>(inputs, embedding, ws, out);
    epilogue_kernel<<<NROWS / 256, 256, 0, stream>>>(inputs, embedding, out, ws);
    finalize_cs<<<1, 1024, 0, stream>>>(cluster, out, ws);
    finalize_emb<<<VQSIZE * DIM / 256, 256, 0, stream>>>(emb_avg, out, ws);
}